// Round 1
// baseline (1143.240 us; speedup 1.0000x reference)
//
#include <hip/hip_runtime.h>
#include <math.h>

#define D_MODEL 512
#define D_INNER 1024
#define D_STATE 16
#define DT_RANK 32
#define B_SZ 2
#define SEQ 2048
#define ROWS (B_SZ*SEQ)   // 4096
#define EPSV 1e-5f

// ---------------- RMSNorm + mask ----------------
__global__ __launch_bounds__(256) void rmsnorm_kernel(const float* __restrict__ x,
        const int* __restrict__ mask, const float* __restrict__ w, float* __restrict__ h) {
    int row = blockIdx.x;
    int tid = threadIdx.x;
    const float2 v = reinterpret_cast<const float2*>(x + (size_t)row * D_MODEL)[tid];
    float ss = v.x * v.x + v.y * v.y;
    #pragma unroll
    for (int m = 1; m < 64; m <<= 1) ss += __shfl_xor(ss, m);
    __shared__ float red[4];
    if ((tid & 63) == 0) red[tid >> 6] = ss;
    __syncthreads();
    float tot = red[0] + red[1] + red[2] + red[3];
    float scale = rsqrtf(tot * (1.0f / D_MODEL) + EPSV) * (float)mask[row];
    float2 o;
    o.x = v.x * scale * w[2 * tid];
    o.y = v.y * scale * w[2 * tid + 1];
    reinterpret_cast<float2*>(h + (size_t)row * D_MODEL)[tid] = o;
}

// ---------------- Generic fp32 GEMM: C[m,n] = sum_k A[m,k]*B[n,k] ----------------
// MODE 0: plain   MODE 1: softplus(acc + bias[n])   MODE 2: xres[m,n] + mask[m]*acc
template<int MODE>
__global__ __launch_bounds__(256) void gemm_nt(const float* __restrict__ A, int lda,
        const float* __restrict__ B, int ldb,
        float* C, int ldc,
        int M, int N, int K,
        const float* __restrict__ bias,
        const float* __restrict__ xres,
        const int* __restrict__ mask2) {
    const int BM = 64, BN = 64, BK = 16;
    __shared__ float As[BK][BM + 1];
    __shared__ float Bs[BK][BN + 1];
    int tid = threadIdx.x;
    int tx = tid & 15, ty = tid >> 4;
    int m0 = blockIdx.y * BM, n0 = blockIdx.x * BN;
    float acc[4][4] = {};
    for (int k0 = 0; k0 < K; k0 += BK) {
        int r = tid >> 2;
        int c = (tid & 3) * 4;
        float4 va = *reinterpret_cast<const float4*>(A + (size_t)(m0 + r) * lda + k0 + c);
        As[c + 0][r] = va.x; As[c + 1][r] = va.y; As[c + 2][r] = va.z; As[c + 3][r] = va.w;
        float4 vb = *reinterpret_cast<const float4*>(B + (size_t)(n0 + r) * ldb + k0 + c);
        Bs[c + 0][r] = vb.x; Bs[c + 1][r] = vb.y; Bs[c + 2][r] = vb.z; Bs[c + 3][r] = vb.w;
        __syncthreads();
        #pragma unroll
        for (int kk = 0; kk < BK; ++kk) {
            float a[4], b[4];
            #pragma unroll
            for (int i = 0; i < 4; ++i) a[i] = As[kk][ty * 4 + i];
            #pragma unroll
            for (int j = 0; j < 4; ++j) b[j] = Bs[kk][tx * 4 + j];
            #pragma unroll
            for (int i = 0; i < 4; ++i)
                #pragma unroll
                for (int j = 0; j < 4; ++j)
                    acc[i][j] = fmaf(a[i], b[j], acc[i][j]);
        }
        __syncthreads();
    }
    #pragma unroll
    for (int i = 0; i < 4; ++i) {
        int m = m0 + ty * 4 + i;
        int n = n0 + tx * 4;
        float r[4] = {acc[i][0], acc[i][1], acc[i][2], acc[i][3]};
        if (MODE == 1) {
            #pragma unroll
            for (int j = 0; j < 4; ++j) {
                float v = r[j] + bias[n + j];
                r[j] = (v > 20.f) ? v : log1pf(expf(v));
            }
        } else if (MODE == 2) {
            float mf = (float)mask2[m];
            #pragma unroll
            for (int j = 0; j < 4; ++j)
                r[j] = xres[(size_t)m * ldc + n + j] + mf * r[j];
        }
        float4 o; o.x = r[0]; o.y = r[1]; o.z = r[2]; o.w = r[3];
        *reinterpret_cast<float4*>(C + (size_t)m * ldc + n) = o;
    }
}

// ---------------- causal depthwise conv (width 4) + bias + SiLU ----------------
__global__ __launch_bounds__(256) void conv_silu_kernel(const float* __restrict__ xz,
        const float* __restrict__ conv_w, const float* __restrict__ conv_b,
        float* __restrict__ u) {
    int idx = blockIdx.x * blockDim.x + threadIdx.x;   // over ROWS*D_INNER
    int d = idx & (D_INNER - 1);
    int row = idx >> 10;           // b*SEQ + t
    int t = row & (SEQ - 1);
    const float* base = xz + (size_t)(row - t) * (2 * D_INNER) + d;  // b's start, column d
    float s = conv_b[d];
    #pragma unroll
    for (int j = 0; j < 4; ++j) {
        int tt = t - 3 + j;
        if (tt >= 0) s = fmaf(conv_w[d * 4 + j], base[(size_t)tt * (2 * D_INNER)], s);
    }
    u[idx] = s / (1.f + __expf(-s));   // SiLU
}

// ---------------- selective scan (16 lanes per (b,d), lane = state) ----------------
// y aliases dt (written after dt[t+1] prefetch, same wave) -> no __restrict__ on those
__global__ __launch_bounds__(256) void scan_kernel(
        const float* dtbuf,                 // (ROWS, D_INNER)
        const float* __restrict__ ubuf,     // (ROWS, D_INNER)
        const float* __restrict__ xdbc,     // (ROWS, 64): [0:32) dt_r, [32:48) B, [48:64) C
        const float* __restrict__ xz,       // (ROWS, 2048): z = cols [1024:2048)
        const float* __restrict__ A_log,    // (D_INNER, D_STATE)
        const float* __restrict__ Dw,       // (D_INNER)
        float* ybuf) {                      // (ROWS, D_INNER), aliases dtbuf
    int tid = threadIdx.x;
    int g = tid >> 4;          // group within block: 16 groups
    int s = tid & 15;          // state index
    int pair = blockIdx.x * 16 + g;   // (b,d) pair, 0..2047
    int b = pair >> 10;
    int d = pair & 1023;
    float Aval = -expf(A_log[d * D_STATE + s]);
    float Dd = Dw[d];
    float state = 0.f;
    size_t rb = (size_t)b * SEQ;
    const float* dtp = dtbuf + rb * D_INNER + d;
    const float* up  = ubuf  + rb * D_INNER + d;
    const float* bp  = xdbc + rb * 64 + 32 + s;
    const float* cp  = xdbc + rb * 64 + 48 + s;
    const float* zp  = xz + rb * (2 * D_INNER) + D_INNER + d;
    float* yp = ybuf + rb * D_INNER + d;

    float dt_c = dtp[0], u_c = up[0], B_c = bp[0], C_c = cp[0], z_c = zp[0];
    for (int t = 0; t < SEQ; ++t) {
        float dt_n = 0.f, u_n = 0.f, B_n = 0.f, C_n = 0.f, z_n = 0.f;
        if (t + 1 < SEQ) {
            size_t r1 = (size_t)(t + 1);
            dt_n = dtp[r1 * D_INNER];
            u_n  = up[r1 * D_INNER];
            B_n  = bp[r1 * 64];
            C_n  = cp[r1 * 64];
            z_n  = zp[r1 * (2 * D_INNER)];
        }
        float dA = __expf(dt_c * Aval);
        state = fmaf(dA, state, dt_c * B_c * u_c);
        float yv = state * C_c;
        yv += __shfl_xor(yv, 1);
        yv += __shfl_xor(yv, 2);
        yv += __shfl_xor(yv, 4);
        yv += __shfl_xor(yv, 8);
        if (s == 0) {
            float sig = 1.f / (1.f + __expf(-z_c));
            yp[(size_t)t * D_INNER] = (yv + Dd * u_c) * (z_c * sig);
        }
        dt_c = dt_n; u_c = u_n; B_c = B_n; C_c = C_n; z_c = z_n;
    }
}

extern "C" void kernel_launch(void* const* d_in, const int* in_sizes, int n_in,
                              void* d_out, int out_size, void* d_ws, size_t ws_size,
                              hipStream_t stream) {
    const float* x          = (const float*)d_in[0];
    const int*   mask       = (const int*)d_in[1];
    const float* norm_w     = (const float*)d_in[2];
    const float* in_proj_w  = (const float*)d_in[3];
    const float* conv_w     = (const float*)d_in[4];
    const float* conv_b     = (const float*)d_in[5];
    const float* x_proj_w   = (const float*)d_in[6];
    const float* dt_proj_w  = (const float*)d_in[7];
    const float* dt_proj_b  = (const float*)d_in[8];
    const float* A_log      = (const float*)d_in[9];
    const float* Dw         = (const float*)d_in[10];
    const float* out_proj_w = (const float*)d_in[11];
    float* out = (float*)d_out;
    float* ws  = (float*)d_ws;

    // workspace layout (floats): total 18,874,368 floats = 72 MiB
    float* h    = ws;                  // ROWS*512  = 2,097,152  (reused for xdbc later)
    float* xz   = ws + 2097152;        // ROWS*2048 = 8,388,608
    float* u    = ws + 10485760;       // ROWS*1024 = 4,194,304
    float* dt   = ws + 14680064;       // ROWS*1024 = 4,194,304  (y aliases dt)
    float* xdbc = h;                   // ROWS*64 = 262,144 fits in h's 2M floats
    float* y    = dt;

    // 1. RMSNorm + mask
    rmsnorm_kernel<<<ROWS, 256, 0, stream>>>(x, mask, norm_w, h);
    // 2. in_proj: (4096x512) x (2048x512)^T -> xz (4096x2048)
    gemm_nt<0><<<dim3(2048 / 64, ROWS / 64), 256, 0, stream>>>(
        h, D_MODEL, in_proj_w, D_MODEL, xz, 2 * D_INNER, ROWS, 2 * D_INNER, D_MODEL,
        nullptr, nullptr, nullptr);
    // 3. causal depthwise conv + SiLU -> u (4096x1024)
    conv_silu_kernel<<<(ROWS * D_INNER) / 256, 256, 0, stream>>>(xz, conv_w, conv_b, u);
    // 4. x_proj: (4096x1024) x (64x1024)^T -> xdbc (4096x64)
    gemm_nt<0><<<dim3(64 / 64, ROWS / 64), 256, 0, stream>>>(
        u, D_INNER, x_proj_w, D_INNER, xdbc, 64, ROWS, 64, D_INNER,
        nullptr, nullptr, nullptr);
    // 5. dt_proj + bias + softplus: (4096x32 [stride 64]) x (1024x32)^T -> dt (4096x1024)
    gemm_nt<1><<<dim3(D_INNER / 64, ROWS / 64), 256, 0, stream>>>(
        xdbc, 64, dt_proj_w, DT_RANK, dt, D_INNER, ROWS, D_INNER, DT_RANK,
        dt_proj_b, nullptr, nullptr);
    // 6. selective scan (+ D*u skip + SiLU(z) gating) -> y (aliases dt)
    scan_kernel<<<(B_SZ * D_INNER) / 16, 256, 0, stream>>>(dt, u, xdbc, xz, A_log, Dw, y);
    // 7. out_proj + residual + mask: (4096x1024) x (512x1024)^T -> out (4096x512)
    gemm_nt<2><<<dim3(D_MODEL / 64, ROWS / 64), 256, 0, stream>>>(
        y, D_INNER, out_proj_w, D_INNER, out, D_MODEL, ROWS, D_MODEL, D_INNER,
        nullptr, x, mask);
}

// Round 2
// 524.718 us; speedup vs baseline: 2.1788x; 2.1788x over previous
//
#include <hip/hip_runtime.h>
#include <math.h>

#define D_MODEL 512
#define D_INNER 1024
#define D_STATE 16
#define DT_RANK 32
#define B_SZ 2
#define SEQ 2048
#define ROWS (B_SZ*SEQ)   // 4096
#define EPSV 1e-5f
#define NCHUNK 16
#define CLEN (SEQ/NCHUNK)   // 128
#define NPAIR (B_SZ*D_INNER) // 2048

// ---------------- RMSNorm + mask ----------------
__global__ __launch_bounds__(256) void rmsnorm_kernel(const float* __restrict__ x,
        const int* __restrict__ mask, const float* __restrict__ w, float* __restrict__ h) {
    int row = blockIdx.x;
    int tid = threadIdx.x;
    const float2 v = reinterpret_cast<const float2*>(x + (size_t)row * D_MODEL)[tid];
    float ss = v.x * v.x + v.y * v.y;
    #pragma unroll
    for (int m = 1; m < 64; m <<= 1) ss += __shfl_xor(ss, m);
    __shared__ float red[4];
    if ((tid & 63) == 0) red[tid >> 6] = ss;
    __syncthreads();
    float tot = red[0] + red[1] + red[2] + red[3];
    float scale = rsqrtf(tot * (1.0f / D_MODEL) + EPSV) * (float)mask[row];
    float2 o;
    o.x = v.x * scale * w[2 * tid];
    o.y = v.y * scale * w[2 * tid + 1];
    reinterpret_cast<float2*>(h + (size_t)row * D_MODEL)[tid] = o;
}

// ---------------- Generic fp32 GEMM: C[m,n] = sum_k A[m,k]*B[n,k] ----------------
// MODE 0: plain   MODE 1: softplus(acc + bias[n])   MODE 2: xres[m,n] + mask[m]*acc
template<int MODE>
__global__ __launch_bounds__(256) void gemm_nt(const float* __restrict__ A, int lda,
        const float* __restrict__ B, int ldb,
        float* C, int ldc,
        int M, int N, int K,
        const float* __restrict__ bias,
        const float* __restrict__ xres,
        const int* __restrict__ mask2) {
    const int BM = 64, BN = 64, BK = 16;
    __shared__ float As[BK][BM + 1];
    __shared__ float Bs[BK][BN + 1];
    int tid = threadIdx.x;
    int tx = tid & 15, ty = tid >> 4;
    int m0 = blockIdx.y * BM, n0 = blockIdx.x * BN;
    float acc[4][4] = {};
    for (int k0 = 0; k0 < K; k0 += BK) {
        int r = tid >> 2;
        int c = (tid & 3) * 4;
        float4 va = *reinterpret_cast<const float4*>(A + (size_t)(m0 + r) * lda + k0 + c);
        As[c + 0][r] = va.x; As[c + 1][r] = va.y; As[c + 2][r] = va.z; As[c + 3][r] = va.w;
        float4 vb = *reinterpret_cast<const float4*>(B + (size_t)(n0 + r) * ldb + k0 + c);
        Bs[c + 0][r] = vb.x; Bs[c + 1][r] = vb.y; Bs[c + 2][r] = vb.z; Bs[c + 3][r] = vb.w;
        __syncthreads();
        #pragma unroll
        for (int kk = 0; kk < BK; ++kk) {
            float a[4], b[4];
            #pragma unroll
            for (int i = 0; i < 4; ++i) a[i] = As[kk][ty * 4 + i];
            #pragma unroll
            for (int j = 0; j < 4; ++j) b[j] = Bs[kk][tx * 4 + j];
            #pragma unroll
            for (int i = 0; i < 4; ++i)
                #pragma unroll
                for (int j = 0; j < 4; ++j)
                    acc[i][j] = fmaf(a[i], b[j], acc[i][j]);
        }
        __syncthreads();
    }
    #pragma unroll
    for (int i = 0; i < 4; ++i) {
        int m = m0 + ty * 4 + i;
        int n = n0 + tx * 4;
        float r[4] = {acc[i][0], acc[i][1], acc[i][2], acc[i][3]};
        if (MODE == 1) {
            #pragma unroll
            for (int j = 0; j < 4; ++j) {
                float v = r[j] + bias[n + j];
                r[j] = (v > 20.f) ? v : log1pf(expf(v));
            }
        } else if (MODE == 2) {
            float mf = (float)mask2[m];
            #pragma unroll
            for (int j = 0; j < 4; ++j)
                r[j] = xres[(size_t)m * ldc + n + j] + mf * r[j];
        }
        float4 o; o.x = r[0]; o.y = r[1]; o.z = r[2]; o.w = r[3];
        *reinterpret_cast<float4*>(C + (size_t)m * ldc + n) = o;
    }
}

// ---------------- causal depthwise conv (width 4) + bias + SiLU ----------------
__global__ __launch_bounds__(256) void conv_silu_kernel(const float* __restrict__ xz,
        const float* __restrict__ conv_w, const float* __restrict__ conv_b,
        float* __restrict__ u) {
    int idx = blockIdx.x * blockDim.x + threadIdx.x;   // over ROWS*D_INNER
    int d = idx & (D_INNER - 1);
    int row = idx >> 10;           // b*SEQ + t
    int t = row & (SEQ - 1);
    const float* base = xz + (size_t)(row - t) * (2 * D_INNER) + d;  // b's start, column d
    float s = conv_b[d];
    #pragma unroll
    for (int j = 0; j < 4; ++j) {
        int tt = t - 3 + j;
        if (tt >= 0) s = fmaf(conv_w[d * 4 + j], base[(size_t)tt * (2 * D_INNER)], s);
    }
    u[idx] = s / (1.f + __expf(-s));   // SiLU
}

// ================= chunked selective scan =================
// Recurrence per (b,d,s): h[t] = dA[t]*h[t-1] + dt[t]*B[t]*u[t]
// Phase 1: per chunk, P = prod(dA), F = local final state (h0=0)
// Phase 2: scan over chunks -> Hinit per chunk
// Phase 3: replay chunk from Hinit, emit gated y

// group = 16 lanes (s); d-fast mapping: blockIdx = c*128 + pb, pair = pb*16+g
__global__ __launch_bounds__(256) void scan_phase1(
        const float* __restrict__ dtbuf, const float* __restrict__ ubuf,
        const float* __restrict__ xdbc, const float* __restrict__ A_log,
        float* __restrict__ P, float* __restrict__ F) {
    int tid = threadIdx.x;
    int g = tid >> 4, s = tid & 15;
    int c = blockIdx.x >> 7;
    int pair = ((blockIdx.x & 127) << 4) | g;
    int b = pair >> 10, d = pair & 1023;
    float Aval = -expf(A_log[d * D_STATE + s]);
    size_t rb = (size_t)b * SEQ + (size_t)c * CLEN;
    const float* dtp = dtbuf + rb * D_INNER + d;
    const float* up  = ubuf  + rb * D_INNER + d;
    const float* bp  = xdbc + rb * 64 + 32 + s;
    float p = 1.f, f = 0.f;
    for (int t = 0; t < CLEN; ++t) {
        float dtv = dtp[(size_t)t * D_INNER];
        float uv  = up[(size_t)t * D_INNER];
        float Bv  = bp[(size_t)t * 64];
        float dA = __expf(dtv * Aval);
        p *= dA;
        f = fmaf(dA, f, dtv * Bv * uv);
    }
    int o = (pair * NCHUNK + c) * D_STATE + s;
    P[o] = p; F[o] = f;
}

// one thread per (pair, s): 16-step serial scan over chunk summaries
__global__ __launch_bounds__(256) void scan_phase2(
        const float* __restrict__ P, const float* __restrict__ F,
        float* __restrict__ Hinit) {
    int idx = blockIdx.x * blockDim.x + threadIdx.x;   // NPAIR*16
    int pair = idx >> 4, s = idx & 15;
    float h = 0.f;
    #pragma unroll
    for (int c = 0; c < NCHUNK; ++c) {
        int o = (pair * NCHUNK + c) * D_STATE + s;
        Hinit[o] = h;
        h = fmaf(P[o], h, F[o]);
    }
}

// ybuf aliases dtbuf: group reads dt[t] (wave program order) before lane0 stores y[t];
// each (b,d,chunk) column range is touched by exactly one group. No __restrict__ on those.
__global__ __launch_bounds__(256) void scan_phase3(
        const float* dtbuf,
        const float* __restrict__ ubuf,
        const float* __restrict__ xdbc,
        const float* __restrict__ xz,
        const float* __restrict__ A_log,
        const float* __restrict__ Dw,
        const float* __restrict__ Hinit,
        float* ybuf) {
    int tid = threadIdx.x;
    int g = tid >> 4, s = tid & 15;
    int c = blockIdx.x >> 7;
    int pair = ((blockIdx.x & 127) << 4) | g;
    int b = pair >> 10, d = pair & 1023;
    float Aval = -expf(A_log[d * D_STATE + s]);
    float Dd = Dw[d];
    float state = Hinit[(pair * NCHUNK + c) * D_STATE + s];
    size_t rb = (size_t)b * SEQ + (size_t)c * CLEN;
    const float* dtp = dtbuf + rb * D_INNER + d;
    const float* up  = ubuf  + rb * D_INNER + d;
    const float* bp  = xdbc + rb * 64 + 32 + s;
    const float* cp  = xdbc + rb * 64 + 48 + s;
    const float* zp  = xz + rb * (2 * D_INNER) + D_INNER + d;
    float* yp = ybuf + rb * D_INNER + d;
    for (int t = 0; t < CLEN; ++t) {
        float dtv = dtp[(size_t)t * D_INNER];
        float uv  = up[(size_t)t * D_INNER];
        float Bv  = bp[(size_t)t * 64];
        float Cv  = cp[(size_t)t * 64];
        float zv  = zp[(size_t)t * (2 * D_INNER)];
        float dA = __expf(dtv * Aval);
        state = fmaf(dA, state, dtv * Bv * uv);
        float yv = state * Cv;
        yv += __shfl_xor(yv, 1);
        yv += __shfl_xor(yv, 2);
        yv += __shfl_xor(yv, 4);
        yv += __shfl_xor(yv, 8);
        if (s == 0) {
            float sig = 1.f / (1.f + __expf(-zv));
            yp[(size_t)t * D_INNER] = (yv + Dd * uv) * (zv * sig);
        }
    }
}

extern "C" void kernel_launch(void* const* d_in, const int* in_sizes, int n_in,
                              void* d_out, int out_size, void* d_ws, size_t ws_size,
                              hipStream_t stream) {
    const float* x          = (const float*)d_in[0];
    const int*   mask       = (const int*)d_in[1];
    const float* norm_w     = (const float*)d_in[2];
    const float* in_proj_w  = (const float*)d_in[3];
    const float* conv_w     = (const float*)d_in[4];
    const float* conv_b     = (const float*)d_in[5];
    const float* x_proj_w   = (const float*)d_in[6];
    const float* dt_proj_w  = (const float*)d_in[7];
    const float* dt_proj_b  = (const float*)d_in[8];
    const float* A_log      = (const float*)d_in[9];
    const float* Dw         = (const float*)d_in[10];
    const float* out_proj_w = (const float*)d_in[11];
    float* out = (float*)d_out;
    float* ws  = (float*)d_ws;

    // workspace layout (floats): total 18,874,368 floats = 72 MiB
    float* h    = ws;                  // ROWS*512  = 2,097,152  (reused below)
    float* xz   = ws + 2097152;        // ROWS*2048 = 8,388,608
    float* u    = ws + 10485760;       // ROWS*1024 = 4,194,304
    float* dt   = ws + 14680064;       // ROWS*1024 = 4,194,304  (y aliases dt)
    // h is dead after in_proj; carve xdbc + scan scratch out of it:
    float* xdbc  = h;                  // ROWS*64            = 262,144
    float* Pbuf  = h + 262144;         // NPAIR*NCHUNK*16    = 524,288
    float* Fbuf  = h + 786432;         // 524,288
    float* Hinit = h + 1310720;        // 524,288  (ends at 1,835,008 < 2,097,152)
    float* y     = dt;

    // 1. RMSNorm + mask
    rmsnorm_kernel<<<ROWS, 256, 0, stream>>>(x, mask, norm_w, h);
    // 2. in_proj: (4096x512) x (2048x512)^T -> xz (4096x2048)
    gemm_nt<0><<<dim3(2048 / 64, ROWS / 64), 256, 0, stream>>>(
        h, D_MODEL, in_proj_w, D_MODEL, xz, 2 * D_INNER, ROWS, 2 * D_INNER, D_MODEL,
        nullptr, nullptr, nullptr);
    // 3. causal depthwise conv + SiLU -> u (4096x1024)
    conv_silu_kernel<<<(ROWS * D_INNER) / 256, 256, 0, stream>>>(xz, conv_w, conv_b, u);
    // 4. x_proj: (4096x1024) x (64x1024)^T -> xdbc (4096x64)
    gemm_nt<0><<<dim3(64 / 64, ROWS / 64), 256, 0, stream>>>(
        u, D_INNER, x_proj_w, D_INNER, xdbc, 64, ROWS, 64, D_INNER,
        nullptr, nullptr, nullptr);
    // 5. dt_proj + bias + softplus: (4096x32 [stride 64]) x (1024x32)^T -> dt (4096x1024)
    gemm_nt<1><<<dim3(D_INNER / 64, ROWS / 64), 256, 0, stream>>>(
        xdbc, 64, dt_proj_w, DT_RANK, dt, D_INNER, ROWS, D_INNER, DT_RANK,
        dt_proj_b, nullptr, nullptr);
    // 6. chunked selective scan (+ D*u skip + SiLU(z) gating) -> y (aliases dt)
    scan_phase1<<<NCHUNK * (NPAIR / 16), 256, 0, stream>>>(dt, u, xdbc, A_log, Pbuf, Fbuf);
    scan_phase2<<<(NPAIR * 16) / 256, 256, 0, stream>>>(Pbuf, Fbuf, Hinit);
    scan_phase3<<<NCHUNK * (NPAIR / 16), 256, 0, stream>>>(dt, u, xdbc, xz, A_log, Dw,
                                                           Hinit, y);
    // 7. out_proj + residual + mask: (4096x1024) x (512x1024)^T -> out (4096x512)
    gemm_nt<2><<<dim3(D_MODEL / 64, ROWS / 64), 256, 0, stream>>>(
        y, D_INNER, out_proj_w, D_INNER, out, D_MODEL, ROWS, D_MODEL, D_INNER,
        nullptr, x, mask);
}

// Round 3
// 329.067 us; speedup vs baseline: 3.4742x; 1.5946x over previous
//
#include <hip/hip_runtime.h>
#include <hip/hip_bf16.h>
#include <math.h>

#define D_MODEL 512
#define D_INNER 1024
#define D_STATE 16
#define DT_RANK 32
#define B_SZ 2
#define SEQ 2048
#define ROWS (B_SZ*SEQ)   // 4096
#define EPSV 1e-5f
#define NCHUNK 16
#define CLEN (SEQ/NCHUNK)    // 128
#define NPAIR (B_SZ*D_INNER) // 2048

typedef short bf16x8 __attribute__((ext_vector_type(8)));
typedef float f32x4  __attribute__((ext_vector_type(4)));
typedef __hip_bfloat16 bf16_t;

static __device__ __forceinline__ float bf2f(bf16_t v) { return __bfloat162float(v); }

// ---------------- fp32 -> bf16 convert (weights) ----------------
__global__ __launch_bounds__(256) void convert_bf16_kernel(const float* __restrict__ in,
        bf16_t* __restrict__ out, int n4) {
    int i = blockIdx.x * 256 + threadIdx.x;
    if (i >= n4) return;
    float4 v = reinterpret_cast<const float4*>(in)[i];
    bf16_t o[4] = {__float2bfloat16(v.x), __float2bfloat16(v.y),
                   __float2bfloat16(v.z), __float2bfloat16(v.w)};
    reinterpret_cast<ushort4*>(out)[i] = *reinterpret_cast<ushort4*>(o);
}

// ---------------- RMSNorm + mask -> bf16 ----------------
__global__ __launch_bounds__(256) void rmsnorm_kernel(const float* __restrict__ x,
        const int* __restrict__ mask, const float* __restrict__ w, bf16_t* __restrict__ h) {
    int row = blockIdx.x;
    int tid = threadIdx.x;
    const float2 v = reinterpret_cast<const float2*>(x + (size_t)row * D_MODEL)[tid];
    float ss = v.x * v.x + v.y * v.y;
    #pragma unroll
    for (int m = 1; m < 64; m <<= 1) ss += __shfl_xor(ss, m);
    __shared__ float red[4];
    if ((tid & 63) == 0) red[tid >> 6] = ss;
    __syncthreads();
    float tot = red[0] + red[1] + red[2] + red[3];
    float scale = rsqrtf(tot * (1.0f / D_MODEL) + EPSV) * (float)mask[row];
    __hip_bfloat162 o;
    o.x = __float2bfloat16(v.x * scale * w[2 * tid]);
    o.y = __float2bfloat16(v.y * scale * w[2 * tid + 1]);
    reinterpret_cast<__hip_bfloat162*>(h + (size_t)row * D_MODEL)[tid] = o;
}

// ---------------- bf16 MFMA GEMM: C[m,n] = sum_k A[m,k]*B[n,k] ----------------
// A: M x K bf16 row-major; B: N x K bf16 row-major; C fp32.
// MODE 0: plain   MODE 2: C = xres + mask[m]*acc
// 128x128 tile, BK=32, 4 waves (2x2), each wave 64x64 via 4x4 16x16x32 MFMA frags.
template<int MODE>
__global__ __launch_bounds__(256) void gemm_mfma(
        const bf16_t* __restrict__ A, const bf16_t* __restrict__ Bw,
        float* __restrict__ C, int M, int N, int K,
        const float* __restrict__ xres, const int* __restrict__ mask2) {
    __shared__ alignas(16) bf16_t As[128 * 32];
    __shared__ alignas(16) bf16_t Bs[128 * 32];
    const int tid = threadIdx.x;
    const int wid = tid >> 6, lane = tid & 63;
    const int m0 = blockIdx.y * 128, n0 = blockIdx.x * 128;
    const int wr = (wid >> 1) * 64, wc = (wid & 1) * 64;

    f32x4 acc[4][4];
    #pragma unroll
    for (int i = 0; i < 4; ++i)
        #pragma unroll
        for (int j = 0; j < 4; ++j)
            #pragma unroll
            for (int r = 0; r < 4; ++r) acc[i][j][r] = 0.f;

    // staging geometry: chunk c = wid*2+j covers LDS bytes [c*1024, c*1024+1024)
    // lane l -> elem (c*64+l)*8 : row r=(c*64+l)/4, lds colblock = l&3
    // source colblock = (l&3) ^ (r&3)  (XOR involution, matched on read)
    const int rrow = lane & 15, kg = lane >> 4;

    for (int k0 = 0; k0 < K; k0 += 32) {
        #pragma unroll
        for (int j = 0; j < 2; ++j) {
            int c = wid * 2 + j;
            int e = c * 64 + lane;
            int r = e >> 2;
            int cbs = (lane & 3) ^ (r & 3);
            const bf16_t* ga = A  + (size_t)(m0 + r) * K + k0 + cbs * 8;
            const bf16_t* gb = Bw + (size_t)(n0 + r) * K + k0 + cbs * 8;
            __builtin_amdgcn_global_load_lds(
                (const __attribute__((address_space(1))) void*)ga,
                (__attribute__((address_space(3))) void*)(As + c * 512), 16, 0, 0);
            __builtin_amdgcn_global_load_lds(
                (const __attribute__((address_space(1))) void*)gb,
                (__attribute__((address_space(3))) void*)(Bs + c * 512), 16, 0, 0);
        }
        __syncthreads();   // drains vmcnt before barrier (compiler-enforced)

        bf16x8 af[4], bfr[4];
        #pragma unroll
        for (int i = 0; i < 4; ++i) {
            int ra = wr + i * 16 + rrow;
            af[i] = *reinterpret_cast<const bf16x8*>(As + ra * 32 + ((kg ^ (ra & 3)) * 8));
            int rb = wc + i * 16 + rrow;
            bfr[i] = *reinterpret_cast<const bf16x8*>(Bs + rb * 32 + ((kg ^ (rb & 3)) * 8));
        }
        #pragma unroll
        for (int i = 0; i < 4; ++i)
            #pragma unroll
            for (int j = 0; j < 4; ++j)
                acc[i][j] = __builtin_amdgcn_mfma_f32_16x16x32_bf16(af[i], bfr[j], acc[i][j], 0, 0, 0);
        __syncthreads();   // protect LDS overwrite next iter
    }

    // C/D layout: col = lane&15, row = (lane>>4)*4 + reg   [m89-verified]
    #pragma unroll
    for (int i = 0; i < 4; ++i)
        #pragma unroll
        for (int j = 0; j < 4; ++j)
            #pragma unroll
            for (int rg = 0; rg < 4; ++rg) {
                int m = m0 + wr + i * 16 + (lane >> 4) * 4 + rg;
                int n = n0 + wc + j * 16 + (lane & 15);
                float v = acc[i][j][rg];
                if (MODE == 2) v = xres[(size_t)m * N + n] + (float)mask2[m] * v;
                C[(size_t)m * N + n] = v;
            }
}

// ---------------- fp32 VALU GEMM (small): C[m,n] = sum_k A[m,k]*B[n,k] ----------------
// MODE 0: plain   MODE 1: softplus(acc + bias[n])    ABF16: A is bf16
template<int MODE, bool ABF16>
__global__ __launch_bounds__(256) void gemm_nt(const void* __restrict__ Av, int lda,
        const float* __restrict__ B, int ldb,
        float* __restrict__ C, int ldc,
        int M, int N, int K,
        const float* __restrict__ bias) {
    const int BM = 64, BN = 64, BK = 16;
    __shared__ float As[BK][BM + 1];
    __shared__ float Bs[BK][BN + 1];
    int tid = threadIdx.x;
    int tx = tid & 15, ty = tid >> 4;
    int m0 = blockIdx.y * BM, n0 = blockIdx.x * BN;
    float acc[4][4] = {};
    for (int k0 = 0; k0 < K; k0 += BK) {
        int r = tid >> 2;
        int c = (tid & 3) * 4;
        if (ABF16) {
            const ushort* A = (const ushort*)Av;
            ushort4 va = *reinterpret_cast<const ushort4*>(A + (size_t)(m0 + r) * lda + k0 + c);
            As[c + 0][r] = __uint_as_float((unsigned)va.x << 16);
            As[c + 1][r] = __uint_as_float((unsigned)va.y << 16);
            As[c + 2][r] = __uint_as_float((unsigned)va.z << 16);
            As[c + 3][r] = __uint_as_float((unsigned)va.w << 16);
        } else {
            const float* A = (const float*)Av;
            float4 va = *reinterpret_cast<const float4*>(A + (size_t)(m0 + r) * lda + k0 + c);
            As[c + 0][r] = va.x; As[c + 1][r] = va.y; As[c + 2][r] = va.z; As[c + 3][r] = va.w;
        }
        float4 vb = *reinterpret_cast<const float4*>(B + (size_t)(n0 + r) * ldb + k0 + c);
        Bs[c + 0][r] = vb.x; Bs[c + 1][r] = vb.y; Bs[c + 2][r] = vb.z; Bs[c + 3][r] = vb.w;
        __syncthreads();
        #pragma unroll
        for (int kk = 0; kk < BK; ++kk) {
            float a[4], b[4];
            #pragma unroll
            for (int i = 0; i < 4; ++i) a[i] = As[kk][ty * 4 + i];
            #pragma unroll
            for (int j = 0; j < 4; ++j) b[j] = Bs[kk][tx * 4 + j];
            #pragma unroll
            for (int i = 0; i < 4; ++i)
                #pragma unroll
                for (int j = 0; j < 4; ++j)
                    acc[i][j] = fmaf(a[i], b[j], acc[i][j]);
        }
        __syncthreads();
    }
    #pragma unroll
    for (int i = 0; i < 4; ++i) {
        int m = m0 + ty * 4 + i;
        int n = n0 + tx * 4;
        float r[4] = {acc[i][0], acc[i][1], acc[i][2], acc[i][3]};
        if (MODE == 1) {
            #pragma unroll
            for (int j = 0; j < 4; ++j) {
                float v = r[j] + bias[n + j];
                r[j] = (v > 20.f) ? v : log1pf(expf(v));
            }
        }
        float4 o; o.x = r[0]; o.y = r[1]; o.z = r[2]; o.w = r[3];
        *reinterpret_cast<float4*>(C + (size_t)m * ldc + n) = o;
    }
}

// ---------------- causal depthwise conv (width 4) + bias + SiLU -> bf16 ----------------
__global__ __launch_bounds__(256) void conv_silu_kernel(const float* __restrict__ xz,
        const float* __restrict__ conv_w, const float* __restrict__ conv_b,
        bf16_t* __restrict__ u) {
    int idx = blockIdx.x * 256 + threadIdx.x;   // over ROWS*D_INNER/2
    int dp = idx & 511;            // d = 2*dp
    int row = idx >> 9;            // b*SEQ + t
    int t = row & (SEQ - 1);
    const float2* base = reinterpret_cast<const float2*>(xz + (size_t)(row - t) * (2 * D_INNER)) + dp;
    int d0 = 2 * dp;
    float2 s = {conv_b[d0], conv_b[d0 + 1]};
    #pragma unroll
    for (int j = 0; j < 4; ++j) {
        int tt = t - 3 + j;
        if (tt >= 0) {
            float2 vv = base[(size_t)tt * D_INNER];
            s.x = fmaf(conv_w[d0 * 4 + j], vv.x, s.x);
            s.y = fmaf(conv_w[(d0 + 1) * 4 + j], vv.y, s.y);
        }
    }
    __hip_bfloat162 o;
    o.x = __float2bfloat16(s.x / (1.f + __expf(-s.x)));
    o.y = __float2bfloat16(s.y / (1.f + __expf(-s.y)));
    reinterpret_cast<__hip_bfloat162*>(u)[idx] = o;
}

// ================= chunked selective scan =================
__global__ __launch_bounds__(256) void scan_phase1(
        const float* __restrict__ dtbuf, const bf16_t* __restrict__ ubuf,
        const float* __restrict__ xdbc, const float* __restrict__ A_log,
        float* __restrict__ P, float* __restrict__ F) {
    int tid = threadIdx.x;
    int g = tid >> 4, s = tid & 15;
    int c = blockIdx.x >> 7;
    int pair = ((blockIdx.x & 127) << 4) | g;
    int b = pair >> 10, d = pair & 1023;
    float Aval = -expf(A_log[d * D_STATE + s]);
    size_t rb = (size_t)b * SEQ + (size_t)c * CLEN;
    const float* dtp = dtbuf + rb * D_INNER + d;
    const bf16_t* up = ubuf + rb * D_INNER + d;
    const float* bp  = xdbc + rb * 64 + 32 + s;
    float p = 1.f, f = 0.f;
    for (int t = 0; t < CLEN; ++t) {
        float dtv = dtp[(size_t)t * D_INNER];
        float uv  = bf2f(up[(size_t)t * D_INNER]);
        float Bv  = bp[(size_t)t * 64];
        float dA = __expf(dtv * Aval);
        p *= dA;
        f = fmaf(dA, f, dtv * Bv * uv);
    }
    int o = (pair * NCHUNK + c) * D_STATE + s;
    P[o] = p; F[o] = f;
}

__global__ __launch_bounds__(256) void scan_phase2(
        const float* __restrict__ P, const float* __restrict__ F,
        float* __restrict__ Hinit) {
    int idx = blockIdx.x * blockDim.x + threadIdx.x;   // NPAIR*16
    int pair = idx >> 4, s = idx & 15;
    float h = 0.f;
    #pragma unroll
    for (int c = 0; c < NCHUNK; ++c) {
        int o = (pair * NCHUNK + c) * D_STATE + s;
        Hinit[o] = h;
        h = fmaf(P[o], h, F[o]);
    }
}

__global__ __launch_bounds__(256) void scan_phase3(
        const float* __restrict__ dtbuf,
        const bf16_t* __restrict__ ubuf,
        const float* __restrict__ xdbc,
        const float* __restrict__ xz,
        const float* __restrict__ A_log,
        const float* __restrict__ Dw,
        const float* __restrict__ Hinit,
        bf16_t* __restrict__ ybuf) {
    int tid = threadIdx.x;
    int g = tid >> 4, s = tid & 15;
    int c = blockIdx.x >> 7;
    int pair = ((blockIdx.x & 127) << 4) | g;
    int b = pair >> 10, d = pair & 1023;
    float Aval = -expf(A_log[d * D_STATE + s]);
    float Dd = Dw[d];
    float state = Hinit[(pair * NCHUNK + c) * D_STATE + s];
    size_t rb = (size_t)b * SEQ + (size_t)c * CLEN;
    const float* dtp = dtbuf + rb * D_INNER + d;
    const bf16_t* up = ubuf + rb * D_INNER + d;
    const float* bp  = xdbc + rb * 64 + 32 + s;
    const float* cp  = xdbc + rb * 64 + 48 + s;
    const float* zp  = xz + rb * (2 * D_INNER) + D_INNER + d;
    bf16_t* yp = ybuf + rb * D_INNER + d;
    for (int t = 0; t < CLEN; ++t) {
        float dtv = dtp[(size_t)t * D_INNER];
        float uv  = bf2f(up[(size_t)t * D_INNER]);
        float Bv  = bp[(size_t)t * 64];
        float Cv  = cp[(size_t)t * 64];
        float zv  = zp[(size_t)t * (2 * D_INNER)];
        float dA = __expf(dtv * Aval);
        state = fmaf(dA, state, dtv * Bv * uv);
        float yv = state * Cv;
        yv += __shfl_xor(yv, 1);
        yv += __shfl_xor(yv, 2);
        yv += __shfl_xor(yv, 4);
        yv += __shfl_xor(yv, 8);
        if (s == 0) {
            float sig = 1.f / (1.f + __expf(-zv));
            yp[(size_t)t * D_INNER] = __float2bfloat16((yv + Dd * uv) * (zv * sig));
        }
    }
}

extern "C" void kernel_launch(void* const* d_in, const int* in_sizes, int n_in,
                              void* d_out, int out_size, void* d_ws, size_t ws_size,
                              hipStream_t stream) {
    const float* x          = (const float*)d_in[0];
    const int*   mask       = (const int*)d_in[1];
    const float* norm_w     = (const float*)d_in[2];
    const float* in_proj_w  = (const float*)d_in[3];
    const float* conv_w     = (const float*)d_in[4];
    const float* conv_b     = (const float*)d_in[5];
    const float* x_proj_w   = (const float*)d_in[6];
    const float* dt_proj_w  = (const float*)d_in[7];
    const float* dt_proj_b  = (const float*)d_in[8];
    const float* A_log      = (const float*)d_in[9];
    const float* Dw         = (const float*)d_in[10];
    const float* out_proj_w = (const float*)d_in[11];
    float* out = (float*)d_out;
    float* ws  = (float*)d_ws;

    // workspace layout (float units), total 18,874,368 = 72 MiB, lifetime-shared:
    float*  xz     = ws;                       // 8,388,608
    bf16_t* u_bf   = (bf16_t*)(ws + 8388608);  // 4,194,304 bf16 = 2,097,152 f
    float*  dt     = ws + 10485760;            // 4,194,304
    // shared1: h_bf16 (dead after in_proj) | y_bf16 (written in phase3)
    bf16_t* h_bf   = (bf16_t*)(ws + 14680064); // up to 2,097,152 f
    bf16_t* y_bf   = (bf16_t*)(ws + 14680064);
    float*  xdbc   = ws + 16777216;            // 262,144
    // shared2: w_in_bf16 (dead after in_proj) | P/F/Hinit (written in phase1/2)
    bf16_t* w_in   = (bf16_t*)(ws + 17039360); // 1,048,576 bf16 = 524,288 f
    float*  Pbuf   = ws + 17039360;            // 524,288
    float*  Fbuf   = ws + 17563648;            // 524,288
    float*  Hinit  = ws + 18087936;            // 524,288
    bf16_t* w_out  = (bf16_t*)(ws + 18612224); // 524,288 bf16 = 262,144 f

    // 0. weight conversions (fp32 -> bf16)
    convert_bf16_kernel<<<(2 * D_INNER * D_MODEL / 4 + 255) / 256, 256, 0, stream>>>(
        in_proj_w, w_in, 2 * D_INNER * D_MODEL / 4);
    convert_bf16_kernel<<<(D_MODEL * D_INNER / 4 + 255) / 256, 256, 0, stream>>>(
        out_proj_w, w_out, D_MODEL * D_INNER / 4);
    // 1. RMSNorm + mask -> bf16 h
    rmsnorm_kernel<<<ROWS, 256, 0, stream>>>(x, mask, norm_w, h_bf);
    // 2. in_proj MFMA: (4096x512)bf16 x (2048x512)^T bf16 -> xz fp32
    gemm_mfma<0><<<dim3(2048 / 128, ROWS / 128), 256, 0, stream>>>(
        h_bf, w_in, xz, ROWS, 2 * D_INNER, D_MODEL, nullptr, nullptr);
    // 3. causal depthwise conv + SiLU -> u bf16
    conv_silu_kernel<<<(ROWS * D_INNER / 2) / 256, 256, 0, stream>>>(xz, conv_w, conv_b, u_bf);
    // 4. x_proj: (4096x1024)bf16 x (64x1024)^T -> xdbc fp32
    gemm_nt<0, true><<<dim3(64 / 64, ROWS / 64), 256, 0, stream>>>(
        u_bf, D_INNER, x_proj_w, D_INNER, xdbc, 64, ROWS, 64, D_INNER, nullptr);
    // 5. dt_proj + bias + softplus
    gemm_nt<1, false><<<dim3(D_INNER / 64, ROWS / 64), 256, 0, stream>>>(
        xdbc, 64, dt_proj_w, DT_RANK, dt, D_INNER, ROWS, D_INNER, DT_RANK, dt_proj_b);
    // 6. chunked selective scan -> y bf16
    scan_phase1<<<NCHUNK * (NPAIR / 16), 256, 0, stream>>>(dt, u_bf, xdbc, A_log, Pbuf, Fbuf);
    scan_phase2<<<(NPAIR * 16) / 256, 256, 0, stream>>>(Pbuf, Fbuf, Hinit);
    scan_phase3<<<NCHUNK * (NPAIR / 16), 256, 0, stream>>>(dt, u_bf, xdbc, xz, A_log, Dw,
                                                           Hinit, y_bf);
    // 7. out_proj MFMA + residual + mask: (4096x1024)bf16 x (512x1024)^T bf16 -> out
    gemm_mfma<2><<<dim3(D_MODEL / 128, ROWS / 128), 256, 0, stream>>>(
        y_bf, w_out, out, ROWS, D_MODEL, D_INNER, x, mask);
}

// Round 4
// 227.749 us; speedup vs baseline: 5.0197x; 1.4449x over previous
//
#include <hip/hip_runtime.h>
#include <hip/hip_bf16.h>
#include <math.h>

#define D_MODEL 512
#define D_INNER 1024
#define D_STATE 16
#define DT_RANK 32
#define B_SZ 2
#define SEQ 2048
#define ROWS (B_SZ*SEQ)   // 4096
#define EPSV 1e-5f
#define NCHUNK 64
#define CLEN (SEQ/NCHUNK)    // 32
#define NPAIR (B_SZ*D_INNER) // 2048
#define LOG2E 1.44269504088896f

typedef short bf16x8 __attribute__((ext_vector_type(8)));
typedef float f32x4  __attribute__((ext_vector_type(4)));
typedef __hip_bfloat16 bf16_t;

static __device__ __forceinline__ float bf2f(bf16_t v) { return __bfloat162float(v); }

// ---------------- fp32 -> bf16 convert (weights) ----------------
__global__ __launch_bounds__(256) void convert_bf16_kernel(const float* __restrict__ in,
        bf16_t* __restrict__ out, int n4) {
    int i = blockIdx.x * 256 + threadIdx.x;
    if (i >= n4) return;
    float4 v = reinterpret_cast<const float4*>(in)[i];
    bf16_t o[4] = {__float2bfloat16(v.x), __float2bfloat16(v.y),
                   __float2bfloat16(v.z), __float2bfloat16(v.w)};
    reinterpret_cast<ushort4*>(out)[i] = *reinterpret_cast<ushort4*>(o);
}

// ---------------- RMSNorm + mask -> bf16 ----------------
__global__ __launch_bounds__(256) void rmsnorm_kernel(const float* __restrict__ x,
        const int* __restrict__ mask, const float* __restrict__ w, bf16_t* __restrict__ h) {
    int row = blockIdx.x;
    int tid = threadIdx.x;
    const float2 v = reinterpret_cast<const float2*>(x + (size_t)row * D_MODEL)[tid];
    float ss = v.x * v.x + v.y * v.y;
    #pragma unroll
    for (int m = 1; m < 64; m <<= 1) ss += __shfl_xor(ss, m);
    __shared__ float red[4];
    if ((tid & 63) == 0) red[tid >> 6] = ss;
    __syncthreads();
    float tot = red[0] + red[1] + red[2] + red[3];
    float scale = rsqrtf(tot * (1.0f / D_MODEL) + EPSV) * (float)mask[row];
    __hip_bfloat162 o;
    o.x = __float2bfloat16(v.x * scale * w[2 * tid]);
    o.y = __float2bfloat16(v.y * scale * w[2 * tid + 1]);
    reinterpret_cast<__hip_bfloat162*>(h + (size_t)row * D_MODEL)[tid] = o;
}

// ---------------- bf16 MFMA GEMM: C[m,n] = sum_k A[m,k]*B[n,k] ----------------
// MODE 2: C fp32 = xres + mask[m]*acc (ldc = N)
// MODE 3: split epilogue: cols [0,1024) -> bf16 u_pre (ld 1024); [1024,2048) -> fp32 z (ld 1024)
template<int MODE>
__global__ __launch_bounds__(256) void gemm_mfma(
        const bf16_t* __restrict__ A, const bf16_t* __restrict__ Bw,
        void* __restrict__ Cv, int M, int N, int K,
        const float* __restrict__ xres, const int* __restrict__ mask2,
        float* __restrict__ z2) {
    __shared__ alignas(16) bf16_t As[128 * 32];
    __shared__ alignas(16) bf16_t Bs[128 * 32];
    const int tid = threadIdx.x;
    const int wid = tid >> 6, lane = tid & 63;
    const int m0 = blockIdx.y * 128, n0 = blockIdx.x * 128;
    const int wr = (wid >> 1) * 64, wc = (wid & 1) * 64;

    f32x4 acc[4][4];
    #pragma unroll
    for (int i = 0; i < 4; ++i)
        #pragma unroll
        for (int j = 0; j < 4; ++j)
            #pragma unroll
            for (int r = 0; r < 4; ++r) acc[i][j][r] = 0.f;

    const int rrow = lane & 15, kg = lane >> 4;

    for (int k0 = 0; k0 < K; k0 += 32) {
        #pragma unroll
        for (int j = 0; j < 2; ++j) {
            int c = wid * 2 + j;
            int e = c * 64 + lane;
            int r = e >> 2;
            int cbs = (lane & 3) ^ (r & 3);
            const bf16_t* ga = A  + (size_t)(m0 + r) * K + k0 + cbs * 8;
            const bf16_t* gb = Bw + (size_t)(n0 + r) * K + k0 + cbs * 8;
            __builtin_amdgcn_global_load_lds(
                (const __attribute__((address_space(1))) void*)ga,
                (__attribute__((address_space(3))) void*)(As + c * 512), 16, 0, 0);
            __builtin_amdgcn_global_load_lds(
                (const __attribute__((address_space(1))) void*)gb,
                (__attribute__((address_space(3))) void*)(Bs + c * 512), 16, 0, 0);
        }
        __syncthreads();

        bf16x8 af[4], bfr[4];
        #pragma unroll
        for (int i = 0; i < 4; ++i) {
            int ra = wr + i * 16 + rrow;
            af[i] = *reinterpret_cast<const bf16x8*>(As + ra * 32 + ((kg ^ (ra & 3)) * 8));
            int rb = wc + i * 16 + rrow;
            bfr[i] = *reinterpret_cast<const bf16x8*>(Bs + rb * 32 + ((kg ^ (rb & 3)) * 8));
        }
        #pragma unroll
        for (int i = 0; i < 4; ++i)
            #pragma unroll
            for (int j = 0; j < 4; ++j)
                acc[i][j] = __builtin_amdgcn_mfma_f32_16x16x32_bf16(af[i], bfr[j], acc[i][j], 0, 0, 0);
        __syncthreads();
    }

    // C/D layout: col = lane&15, row = (lane>>4)*4 + reg
    #pragma unroll
    for (int i = 0; i < 4; ++i)
        #pragma unroll
        for (int j = 0; j < 4; ++j)
            #pragma unroll
            for (int rg = 0; rg < 4; ++rg) {
                int m = m0 + wr + i * 16 + (lane >> 4) * 4 + rg;
                int n = n0 + wc + j * 16 + (lane & 15);
                float v = acc[i][j][rg];
                if (MODE == 2) {
                    float* C = (float*)Cv;
                    C[(size_t)m * N + n] = xres[(size_t)m * N + n] + (float)mask2[m] * v;
                } else {  // MODE 3: split u(bf16)/z(f32), both stride D_INNER
                    if (n0 < D_INNER)
                        ((bf16_t*)Cv)[(size_t)m * D_INNER + n] = __float2bfloat16(v);
                    else
                        z2[(size_t)m * D_INNER + (n - D_INNER)] = v;
                }
            }
}

// ---------------- fp32 VALU GEMM (small): C[m,n] = sum_k A[m,k]*B[n,k] ----------------
// MODE 0: plain fp32 out   MODE 1: softplus(acc + bias[n]) -> bf16 out    ABF16: A is bf16
template<int MODE, bool ABF16>
__global__ __launch_bounds__(256) void gemm_nt(const void* __restrict__ Av, int lda,
        const float* __restrict__ B, int ldb,
        void* __restrict__ Cv, int ldc,
        int M, int N, int K,
        const float* __restrict__ bias) {
    const int BM = 64, BN = 64, BK = 16;
    __shared__ float As[BK][BM + 4];
    __shared__ float Bs[BK][BN + 4];
    int tid = threadIdx.x;
    int tx = tid & 15, ty = tid >> 4;
    int m0 = blockIdx.y * BM, n0 = blockIdx.x * BN;
    float acc[4][4] = {};
    for (int k0 = 0; k0 < K; k0 += BK) {
        int r = tid >> 2;
        int c = (tid & 3) * 4;
        if (ABF16) {
            const ushort* A = (const ushort*)Av;
            ushort4 va = *reinterpret_cast<const ushort4*>(A + (size_t)(m0 + r) * lda + k0 + c);
            As[c + 0][r] = __uint_as_float((unsigned)va.x << 16);
            As[c + 1][r] = __uint_as_float((unsigned)va.y << 16);
            As[c + 2][r] = __uint_as_float((unsigned)va.z << 16);
            As[c + 3][r] = __uint_as_float((unsigned)va.w << 16);
        } else {
            const float* A = (const float*)Av;
            float4 va = *reinterpret_cast<const float4*>(A + (size_t)(m0 + r) * lda + k0 + c);
            As[c + 0][r] = va.x; As[c + 1][r] = va.y; As[c + 2][r] = va.z; As[c + 3][r] = va.w;
        }
        float4 vb = *reinterpret_cast<const float4*>(B + (size_t)(n0 + r) * ldb + k0 + c);
        Bs[c + 0][r] = vb.x; Bs[c + 1][r] = vb.y; Bs[c + 2][r] = vb.z; Bs[c + 3][r] = vb.w;
        __syncthreads();
        #pragma unroll
        for (int kk = 0; kk < BK; ++kk) {
            float a[4], b[4];
            #pragma unroll
            for (int i = 0; i < 4; ++i) a[i] = As[kk][ty * 4 + i];
            #pragma unroll
            for (int j = 0; j < 4; ++j) b[j] = Bs[kk][tx * 4 + j];
            #pragma unroll
            for (int i = 0; i < 4; ++i)
                #pragma unroll
                for (int j = 0; j < 4; ++j)
                    acc[i][j] = fmaf(a[i], b[j], acc[i][j]);
        }
        __syncthreads();
    }
    #pragma unroll
    for (int i = 0; i < 4; ++i) {
        int m = m0 + ty * 4 + i;
        int n = n0 + tx * 4;
        float r[4] = {acc[i][0], acc[i][1], acc[i][2], acc[i][3]};
        if (MODE == 1) {
            bf16_t o[4];
            #pragma unroll
            for (int j = 0; j < 4; ++j) {
                float v = r[j] + bias[n + j];
                o[j] = __float2bfloat16((v > 20.f) ? v : log1pf(expf(v)));
            }
            *reinterpret_cast<ushort4*>((bf16_t*)Cv + (size_t)m * ldc + n) =
                *reinterpret_cast<ushort4*>(o);
        } else {
            float4 o; o.x = r[0]; o.y = r[1]; o.z = r[2]; o.w = r[3];
            *reinterpret_cast<float4*>((float*)Cv + (size_t)m * ldc + n) = o;
        }
    }
}

// ---------------- causal depthwise conv (width 4) + bias + SiLU, bf16 in/out ----------------
__global__ __launch_bounds__(256) void conv_silu_kernel(const bf16_t* __restrict__ upre,
        const float* __restrict__ conv_w, const float* __restrict__ conv_b,
        bf16_t* __restrict__ u) {
    int idx = blockIdx.x * 256 + threadIdx.x;   // over ROWS*D_INNER/2
    int dp = idx & 511;            // d = 2*dp
    int row = idx >> 9;            // b*SEQ + t
    int t = row & (SEQ - 1);
    const __hip_bfloat162* base =
        reinterpret_cast<const __hip_bfloat162*>(upre + (size_t)(row - t) * D_INNER) + dp;
    int d0 = 2 * dp;
    float sx = conv_b[d0], sy = conv_b[d0 + 1];
    #pragma unroll
    for (int j = 0; j < 4; ++j) {
        int tt = t - 3 + j;
        if (tt >= 0) {
            __hip_bfloat162 vv = base[(size_t)tt * 512];
            sx = fmaf(conv_w[d0 * 4 + j], bf2f(vv.x), sx);
            sy = fmaf(conv_w[(d0 + 1) * 4 + j], bf2f(vv.y), sy);
        }
    }
    __hip_bfloat162 o;
    o.x = __float2bfloat16(sx / (1.f + __expf(-sx)));
    o.y = __float2bfloat16(sy / (1.f + __expf(-sy)));
    reinterpret_cast<__hip_bfloat162*>(u)[idx] = o;
}

// ================= chunked selective scan: 16 states per thread =================
// grid 512: bid -> dblk(2b) | c(6b) | b(1b); thread owns d = dblk*256+tid, states 0..15 in regs.
// B/C for the chunk staged in LDS (shared by all d), broadcast reads.
__global__ __launch_bounds__(256) void scan_phase1(
        const bf16_t* __restrict__ dtb, const bf16_t* __restrict__ ub,
        const float* __restrict__ xdbc, const float* __restrict__ A_log,
        float* __restrict__ P, float* __restrict__ F) {
    int tid = threadIdx.x;
    int bid = blockIdx.x;
    int dblk = bid & 3, c = (bid >> 2) & (NCHUNK - 1), b = bid >> 8;
    int d = dblk * 256 + tid;
    __shared__ float sBC[CLEN][32];
    size_t rb = (size_t)b * SEQ + (size_t)c * CLEN;
    {
        int row = tid >> 3, q = tid & 7;
        *reinterpret_cast<float4*>(&sBC[row][q * 4]) =
            *reinterpret_cast<const float4*>(xdbc + (rb + row) * 64 + 32 + q * 4);
    }
    float A2[16];
    #pragma unroll
    for (int s4 = 0; s4 < 4; ++s4) {
        float4 a = *reinterpret_cast<const float4*>(A_log + d * D_STATE + s4 * 4);
        A2[s4 * 4 + 0] = -expf(a.x) * LOG2E;
        A2[s4 * 4 + 1] = -expf(a.y) * LOG2E;
        A2[s4 * 4 + 2] = -expf(a.z) * LOG2E;
        A2[s4 * 4 + 3] = -expf(a.w) * LOG2E;
    }
    float p[16], f[16];
    #pragma unroll
    for (int s = 0; s < 16; ++s) { p[s] = 1.f; f[s] = 0.f; }
    const bf16_t* dtp = dtb + rb * D_INNER + d;
    const bf16_t* up  = ub  + rb * D_INNER + d;
    __syncthreads();
    float dtv = bf2f(dtp[0]), uv = bf2f(up[0]);
    for (int t = 0; t < CLEN; ++t) {
        int tn = (t + 1 < CLEN) ? t + 1 : t;
        float dt_n = bf2f(dtp[(size_t)tn * D_INNER]);
        float u_n  = bf2f(up[(size_t)tn * D_INNER]);
        float dtu = dtv * uv;
        #pragma unroll
        for (int s = 0; s < 16; ++s) {
            float e = exp2f(dtv * A2[s]);
            p[s] *= e;
            f[s] = fmaf(e, f[s], sBC[t][s] * dtu);
        }
        dtv = dt_n; uv = u_n;
    }
    size_t o = ((size_t)(b * D_INNER + d) * NCHUNK + c) * D_STATE;
    #pragma unroll
    for (int s4 = 0; s4 < 4; ++s4) {
        float4 vp = {p[s4*4+0], p[s4*4+1], p[s4*4+2], p[s4*4+3]};
        float4 vf = {f[s4*4+0], f[s4*4+1], f[s4*4+2], f[s4*4+3]};
        *reinterpret_cast<float4*>(P + o + s4 * 4) = vp;
        *reinterpret_cast<float4*>(F + o + s4 * 4) = vf;
    }
}

// one thread per (pair,s) chain; writes Hinit IN PLACE over P
__global__ __launch_bounds__(256) void scan_phase2(
        float* __restrict__ P, const float* __restrict__ F) {
    int idx = blockIdx.x * 256 + threadIdx.x;   // NPAIR*16
    int pair = idx >> 4, s = idx & 15;
    size_t base = (size_t)pair * NCHUNK * D_STATE + s;
    float h = 0.f;
    for (int c = 0; c < NCHUNK; ++c) {
        size_t o = base + (size_t)c * D_STATE;
        float pp = P[o], ff = F[o];
        P[o] = h;                    // Hinit
        h = fmaf(pp, h, ff);
    }
}

__global__ __launch_bounds__(256) void scan_phase3(
        const bf16_t* __restrict__ dtb, const bf16_t* __restrict__ ub,
        const float* __restrict__ xdbc, const float* __restrict__ zbuf,
        const float* __restrict__ A_log, const float* __restrict__ Dw,
        const float* __restrict__ Hinit, bf16_t* __restrict__ ybuf) {
    int tid = threadIdx.x;
    int bid = blockIdx.x;
    int dblk = bid & 3, c = (bid >> 2) & (NCHUNK - 1), b = bid >> 8;
    int d = dblk * 256 + tid;
    __shared__ float sBC[CLEN][32];
    size_t rb = (size_t)b * SEQ + (size_t)c * CLEN;
    {
        int row = tid >> 3, q = tid & 7;
        *reinterpret_cast<float4*>(&sBC[row][q * 4]) =
            *reinterpret_cast<const float4*>(xdbc + (rb + row) * 64 + 32 + q * 4);
    }
    float A2[16];
    #pragma unroll
    for (int s4 = 0; s4 < 4; ++s4) {
        float4 a = *reinterpret_cast<const float4*>(A_log + d * D_STATE + s4 * 4);
        A2[s4 * 4 + 0] = -expf(a.x) * LOG2E;
        A2[s4 * 4 + 1] = -expf(a.y) * LOG2E;
        A2[s4 * 4 + 2] = -expf(a.z) * LOG2E;
        A2[s4 * 4 + 3] = -expf(a.w) * LOG2E;
    }
    float Dd = Dw[d];
    float st[16];
    size_t o = ((size_t)(b * D_INNER + d) * NCHUNK + c) * D_STATE;
    #pragma unroll
    for (int s4 = 0; s4 < 4; ++s4) {
        float4 hv = *reinterpret_cast<const float4*>(Hinit + o + s4 * 4);
        st[s4*4+0] = hv.x; st[s4*4+1] = hv.y; st[s4*4+2] = hv.z; st[s4*4+3] = hv.w;
    }
    const bf16_t* dtp = dtb + rb * D_INNER + d;
    const bf16_t* up  = ub  + rb * D_INNER + d;
    const float*  zp  = zbuf + rb * D_INNER + d;
    bf16_t* yp = ybuf + rb * D_INNER + d;
    __syncthreads();
    float dtv = bf2f(dtp[0]), uv = bf2f(up[0]), zv = zp[0];
    for (int t = 0; t < CLEN; ++t) {
        int tn = (t + 1 < CLEN) ? t + 1 : t;
        float dt_n = bf2f(dtp[(size_t)tn * D_INNER]);
        float u_n  = bf2f(up[(size_t)tn * D_INNER]);
        float z_n  = zp[(size_t)tn * D_INNER];
        float dtu = dtv * uv;
        float y = 0.f;
        #pragma unroll
        for (int s = 0; s < 16; ++s) {
            float e = exp2f(dtv * A2[s]);
            st[s] = fmaf(e, st[s], sBC[t][s] * dtu);
            y = fmaf(st[s], sBC[t][16 + s], y);
        }
        float sig = 1.f / (1.f + __expf(-zv));
        yp[(size_t)t * D_INNER] = __float2bfloat16((y + Dd * uv) * (zv * sig));
        dtv = dt_n; uv = u_n; zv = z_n;
    }
}

extern "C" void kernel_launch(void* const* d_in, const int* in_sizes, int n_in,
                              void* d_out, int out_size, void* d_ws, size_t ws_size,
                              hipStream_t stream) {
    const float* x          = (const float*)d_in[0];
    const int*   mask       = (const int*)d_in[1];
    const float* norm_w     = (const float*)d_in[2];
    const float* in_proj_w  = (const float*)d_in[3];
    const float* conv_w     = (const float*)d_in[4];
    const float* conv_b     = (const float*)d_in[5];
    const float* x_proj_w   = (const float*)d_in[6];
    const float* dt_proj_w  = (const float*)d_in[7];
    const float* dt_proj_b  = (const float*)d_in[8];
    const float* A_log      = (const float*)d_in[9];
    const float* Dw         = (const float*)d_in[10];
    const float* out_proj_w = (const float*)d_in[11];
    float* out = (float*)d_out;
    float* ws  = (float*)d_ws;

    // workspace layout (float units), lifetime-shared, total 17,301,504 f = 66 MiB:
    bf16_t* u_pre = (bf16_t*)ws;               // ROWS*1024 bf16 = 2,097,152 f
    float*  zbuf  = ws + 2097152;              // ROWS*1024 f32  = 4,194,304 f
    bf16_t* u_bf  = (bf16_t*)(ws + 6291456);   // 2,097,152 f
    bf16_t* dt_bf = (bf16_t*)(ws + 8388608);   // 2,097,152 f
    bf16_t* h_bf  = (bf16_t*)(ws + 10485760);  // shared with y (h dead after in_proj)
    bf16_t* y_bf  = (bf16_t*)(ws + 10485760);  // 2,097,152 f
    float*  xdbc  = ws + 12582912;             // 262,144 f
    float*  Pbuf  = ws + 12845056;             // 2,097,152 f (Hinit in place; w_in aliased)
    bf16_t* w_in  = (bf16_t*)(ws + 12845056);  // 1,048,576 bf16 = 524,288 f (dead before P)
    float*  Fbuf  = ws + 14942208;             // 2,097,152 f
    bf16_t* w_out = (bf16_t*)(ws + 17039360);  // 262,144 f

    // 0. weight conversions
    convert_bf16_kernel<<<1024, 256, 0, stream>>>(in_proj_w, w_in, 2 * D_INNER * D_MODEL / 4);
    convert_bf16_kernel<<<512, 256, 0, stream>>>(out_proj_w, w_out, D_MODEL * D_INNER / 4);
    // 1. RMSNorm + mask -> bf16 h
    rmsnorm_kernel<<<ROWS, 256, 0, stream>>>(x, mask, norm_w, h_bf);
    // 2. in_proj MFMA, split epilogue: u half -> bf16 u_pre, z half -> fp32 zbuf
    gemm_mfma<3><<<dim3(16, 32), 256, 0, stream>>>(
        h_bf, w_in, u_pre, ROWS, 2 * D_INNER, D_MODEL, nullptr, nullptr, zbuf);
    // 3. causal depthwise conv + SiLU -> u bf16
    conv_silu_kernel<<<(ROWS * D_INNER / 2) / 256, 256, 0, stream>>>(u_pre, conv_w, conv_b, u_bf);
    // 4. x_proj: (4096x1024)bf16 x (64x1024)^T fp32 -> xdbc fp32
    gemm_nt<0, true><<<dim3(1, 64), 256, 0, stream>>>(
        u_bf, D_INNER, x_proj_w, D_INNER, xdbc, 64, ROWS, 64, D_INNER, nullptr);
    // 5. dt_proj + bias + softplus -> bf16 dt
    gemm_nt<1, false><<<dim3(16, 64), 256, 0, stream>>>(
        xdbc, 64, dt_proj_w, DT_RANK, dt_bf, D_INNER, ROWS, D_INNER, DT_RANK, dt_proj_b);
    // 6. chunked selective scan -> y bf16
    scan_phase1<<<B_SZ * NCHUNK * 4, 256, 0, stream>>>(dt_bf, u_bf, xdbc, A_log, Pbuf, Fbuf);
    scan_phase2<<<NPAIR * D_STATE / 256, 256, 0, stream>>>(Pbuf, Fbuf);
    scan_phase3<<<B_SZ * NCHUNK * 4, 256, 0, stream>>>(dt_bf, u_bf, xdbc, zbuf, A_log, Dw,
                                                       Pbuf, y_bf);
    // 7. out_proj MFMA + residual + mask
    gemm_mfma<2><<<dim3(4, 32), 256, 0, stream>>>(
        y_bf, w_out, out, ROWS, D_MODEL, D_INNER, x, mask, nullptr);
}